// Round 6
// baseline (264.259 us; speedup 1.0000x reference)
//
#include <hip/hip_runtime.h>

typedef float f4 __attribute__((ext_vector_type(4)));

#define NB 256   // persistent grid: 256 blocks x 256 threads, 1 block/CU

// Monotone ticket barrier counter. __device__ global: zero-init at module load,
// NOT part of d_ws (so harness 0xAA poison can't touch it). Never reset: each
// barrier waits for cnt to reach the next multiple of NB — correct across an
// arbitrary number of graph replays (u64 cannot wrap).
__device__ unsigned long long g_bar;

__device__ __forceinline__ void grid_bar() {
    __syncthreads();
    if (threadIdx.x == 0) {
        __threadfence();  // agent-scope release of this XCD's prior writes
        unsigned long long t = __hip_atomic_fetch_add(&g_bar, 1ull, __ATOMIC_ACQ_REL,
                                                      __HIP_MEMORY_SCOPE_AGENT) + 1ull;
        unsigned long long target = ((t - 1ull) / NB + 1ull) * NB;
        while (__hip_atomic_load(&g_bar, __ATOMIC_ACQUIRE, __HIP_MEMORY_SCOPE_AGENT) < target)
            __builtin_amdgcn_s_sleep(2);
        __threadfence();  // acquire: invalidate stale L1/L2 before next phase's reads
    }
    __syncthreads();
}

// Uniform row pointer into concatenated v_t_d / v_l_d:
// [vmain(384) | v1(64) | v2(32) | v0(64)] along tokens
__device__ __forceinline__ const float* vd_row(const float* vmain, const float* v0,
                                               const float* v1, const float* v2,
                                               int b, int t) {
    if (t < 384)      return vmain + ((size_t)b * 384 + t) * 128;
    else if (t < 448) return v1    + ((size_t)b * 64 + (t - 384)) * 128;
    else if (t < 480) return v2    + ((size_t)b * 32 + (t - 448)) * 128;
    else              return v0    + ((size_t)b * 64 + (t - 480)) * 128;
}

__global__ __launch_bounds__(256, 1) void k_fused(
    const float* __restrict__ v0, const float* __restrict__ v1, const float* __restrict__ v2,
    const float* __restrict__ vt, const float* __restrict__ vl,
    const float* __restrict__ Wt, const float* __restrict__ bt,
    const float* __restrict__ Wl, const float* __restrict__ bl,
    const float* __restrict__ Wa, const float* __restrict__ ba,
    const float* __restrict__ W1, const float* __restrict__ b1,
    const float* __restrict__ W2, const float* __restrict__ b2,
    const float* __restrict__ W3, const float* __restrict__ b3,
    const float* __restrict__ Wo, const float* __restrict__ bo,
    float* __restrict__ out, float* __restrict__ ws)
{
    float* attT = ws;             // [2][2][128][544]  (side,b,d,t) transposed for P2
    float* S    = ws + 278528;    // [2][2][544][128]
    float* gbuf = ws + 557056;    // [2][2][544][128]  gated values, reduced in P4
    float* x    = ws + 835584;    // [2][256]
    float* f1v  = ws + 836096;    // [2][1024]
    float* f2v  = ws + 838144;    // [2][512]

    const int bid = blockIdx.x, tid = threadIdx.x;
    const int h  = tid >> 7, d = tid & 127;   // half-block id, d-lane
    const int hb = bid * 2 + h;               // 0..511
    const int lane = tid & 63, wvid = tid >> 6;
    const int wid = bid * 4 + wvid;           // global wave id 0..1023

    __shared__ float red[4];
    __shared__ float f3s[512];

    // ---------- P1: att — half-block computes 4-5 token rows of one side ----------
    {
        const int side  = hb >> 8;            // blocks 0-127 -> side0, 128-255 -> side1
        const int local = hb & 255;
        const float* W     = side ? Wl : Wt;
        const float* bias  = side ? bl : bt;
        const float* vmain = side ? vl : vt;
        f4 w[32];                              // W row for this thread's d: 128 VGPR
        const f4* wrow = (const f4*)(W + d * 128);
        #pragma unroll
        for (int kc = 0; kc < 32; ++kc) w[kc] = wrow[kc];
        float bv = bias[d];
        for (int j = local; j < 1088; j += 256) {
            int b = j / 544, t = j % 544;
            const float* row = vd_row(vmain, v0, v1, v2, b, t);
            float acc = bv;
            #pragma unroll
            for (int kc = 0; kc < 32; ++kc) {
                f4 rv = *(const f4*)(row + kc * 4);   // broadcast load
                acc += rv[0]*w[kc][0] + rv[1]*w[kc][1] + rv[2]*w[kc][2] + rv[3]*w[kc][3];
            }
            attT[((size_t)(side * 2 + b) * 128 + d) * 544 + t] = acc;
        }
    }
    grid_bar();

    // ---------- P2: pairwise mean — one (so,b,d2) unit per half-block ----------
    // lrelu(x)=0.505x+0.495|x| => sum_l lrelu(c+o[l]) = 0.505*(544c+sum_o)+0.495*sum|c+o[l]|
    {
        const int so = hb >> 8, bb = (hb >> 7) & 1, d2 = hb & 127;
        const float* trow = attT + ((size_t)(0 * 2 + bb) * 128 + d2) * 544;
        const float* lrow = attT + ((size_t)(1 * 2 + bb) * 128 + d2) * 544;
        const float* selfr  = so ? lrow : trow;
        const float* otherr = so ? trow : lrow;
        float p = 0.f;
        for (int i = d; i < 544; i += 128) p += otherr[i];
        #pragma unroll
        for (int off = 32; off > 0; off >>= 1) p += __shfl_down(p, off, 64);
        if (lane == 0) red[wvid] = p;
        __syncthreads();
        float sum_o = red[h * 2] + red[h * 2 + 1];
        for (int t = d; t < 544; t += 128) {
            float c = selfr[t];
            float s = 0.f;
            #pragma unroll 8
            for (int l = 0; l < 544; ++l) s += fabsf(c + otherr[l]);
            S[((size_t)(so * 2 + bb) * 544 + t) * 128 + d2] =
                (0.505f * (544.f * c + sum_o) + 0.495f * s) * (1.0f / 544.f);
        }
    }
    grid_bar();

    // ---------- P3: atte = sigmoid(S @ Wa^T + ba); write atte + gated value ----------
    {
        f4 wa[32];                             // Wa row (shared by both sides)
        const f4* wrow = (const f4*)(Wa + d * 128);
        #pragma unroll
        for (int kc = 0; kc < 32; ++kc) wa[kc] = wrow[kc];
        float bav = ba[d];
        for (int u = hb; u < 2176; u += 512) {
            int side = u / 1088, r = u % 1088;
            int b = r / 544, t = r % 544;
            const float* srow = S + ((size_t)(side * 2 + b) * 544 + t) * 128;
            float acc = bav;
            #pragma unroll
            for (int kc = 0; kc < 32; ++kc) {
                f4 sv = *(const f4*)(srow + kc * 4);  // broadcast load
                acc += sv[0]*wa[kc][0] + sv[1]*wa[kc][1] + sv[2]*wa[kc][2] + sv[3]*wa[kc][3];
            }
            float atte = 1.f / (1.f + expf(-acc));
            out[4 + side * 139264 + ((size_t)b * 544 + t) * 128 + d] = atte;
            const float* vrow = vd_row(side ? vl : vt, v0, v1, v2, b, t);
            gbuf[((size_t)(side * 2 + b) * 544 + t) * 128 + d] = vrow[d] * (0.5f + atte);
        }
    }
    grid_bar();

    // ---------- P4: x[b][c] = sum_t gbuf — one (b,c) unit per wave, no atomics ----------
    if (wid < 512) {
        int b = wid >> 8, c = wid & 255;
        int side = c >> 7, dd = c & 127;
        const float* gp = gbuf + ((size_t)(side * 2 + b) * 544) * 128 + dd;
        float s = 0.f;
        for (int t = lane; t < 544; t += 64) s += gp[(size_t)t * 128];
        #pragma unroll
        for (int off = 32; off > 0; off >>= 1) s += __shfl_down(s, off, 64);
        if (lane == 0) x[b * 256 + c] = s;
    }
    grid_bar();

    // ---------- P5: fc1 (2048 outputs, 2 per wave, K=256 -> 1 f4/lane) ----------
    for (int o2 = wid; o2 < 2048; o2 += 1024) {
        int b = o2 >> 10, o = o2 & 1023;
        f4 wv4 = ((const f4*)(W1 + (size_t)o * 256))[lane];
        f4 iv  = ((const f4*)(x + b * 256))[lane];
        float acc = wv4[0]*iv[0] + wv4[1]*iv[1] + wv4[2]*iv[2] + wv4[3]*iv[3];
        #pragma unroll
        for (int off = 32; off > 0; off >>= 1) acc += __shfl_down(acc, off, 64);
        if (lane == 0) {
            acc += b1[o];
            f1v[o2] = acc > 0.f ? acc : 0.01f * acc;
        }
    }
    grid_bar();

    // ---------- P6: fc2 (1024 outputs, 1 per wave, K=1024 -> 4 f4/lane) ----------
    {
        int b = wid >> 9, o = wid & 511;
        const f4* w2r = (const f4*)(W2 + (size_t)o * 1024);
        const f4* i2r = (const f4*)(f1v + b * 1024);
        float acc = 0.f;
        #pragma unroll
        for (int c2 = 0; c2 < 4; ++c2) {
            f4 wv4 = w2r[c2 * 64 + lane];
            f4 iv  = i2r[c2 * 64 + lane];
            acc += wv4[0]*iv[0] + wv4[1]*iv[1] + wv4[2]*iv[2] + wv4[3]*iv[3];
        }
        #pragma unroll
        for (int off = 32; off > 0; off >>= 1) acc += __shfl_down(acc, off, 64);
        if (lane == 0) {
            acc += b2[o];
            f2v[wid] = acc > 0.f ? acc : 0.01f * acc;
        }
    }
    grid_bar();

    // ---------- P7+P8: fc3 + predict, block 0 only (block-local sync) ----------
    if (bid == 0) {
        const f4* w3r = (const f4*)(W3 + (size_t)tid * 512);
        const f4* f20 = (const f4*)(f2v);
        const f4* f21 = (const f4*)(f2v + 512);
        float a0 = b3[tid], a1 = a0;
        #pragma unroll 4
        for (int c2 = 0; c2 < 128; ++c2) {
            f4 wv4 = w3r[c2];
            f4 i0 = f20[c2];
            f4 i1 = f21[c2];
            a0 += wv4[0]*i0[0] + wv4[1]*i0[1] + wv4[2]*i0[2] + wv4[3]*i0[3];
            a1 += wv4[0]*i1[0] + wv4[1]*i1[1] + wv4[2]*i1[2] + wv4[3]*i1[3];
        }
        f3s[tid]       = a0 > 0.f ? a0 : 0.01f * a0;
        f3s[256 + tid] = a1 > 0.f ? a1 : 0.01f * a1;
        __syncthreads();
        int b = wvid >> 1, o = wvid & 1;       // 4 waves -> 4 outputs
        f4 wo4 = ((const f4*)(Wo + o * 256))[lane];
        float acc = wo4[0]*f3s[b*256 + lane*4]     + wo4[1]*f3s[b*256 + lane*4 + 1]
                  + wo4[2]*f3s[b*256 + lane*4 + 2] + wo4[3]*f3s[b*256 + lane*4 + 3];
        #pragma unroll
        for (int off = 32; off > 0; off >>= 1) acc += __shfl_down(acc, off, 64);
        if (lane == 0) out[b * 2 + o] = acc + bo[o];
    }
}

extern "C" void kernel_launch(void* const* d_in, const int* in_sizes, int n_in,
                              void* d_out, int out_size, void* d_ws, size_t ws_size,
                              hipStream_t stream) {
    (void)in_sizes; (void)n_in; (void)out_size; (void)ws_size;
    k_fused<<<NB, 256, 0, stream>>>(
        (const float*)d_in[0],  (const float*)d_in[1],  (const float*)d_in[2],
        (const float*)d_in[3],  (const float*)d_in[4],
        (const float*)d_in[5],  (const float*)d_in[6],
        (const float*)d_in[7],  (const float*)d_in[8],
        (const float*)d_in[9],  (const float*)d_in[10],
        (const float*)d_in[11], (const float*)d_in[12],
        (const float*)d_in[13], (const float*)d_in[14],
        (const float*)d_in[15], (const float*)d_in[16],
        (const float*)d_in[17], (const float*)d_in[18],
        (float*)d_out, (float*)d_ws);
}

// Round 7
// 91.796 us; speedup vs baseline: 2.8788x; 2.8788x over previous
//
#include <hip/hip_runtime.h>

typedef float f4 __attribute__((ext_vector_type(4)));

// Uniform (per-block) row pointer into concatenated v_t_d / v_l_d:
// [vmain(384) | v1(64) | v2(32) | v0(64)] along tokens
__device__ __forceinline__ const float* vd_row(const float* vmain, const float* v0,
                                               const float* v1, const float* v2,
                                               int b, int t) {
    if (t < 384)      return vmain + ((size_t)b * 384 + t) * 128;
    else if (t < 448) return v1    + ((size_t)b * 64 + (t - 384)) * 128;
    else if (t < 480) return v2    + ((size_t)b * 32 + (t - 448)) * 128;
    else              return v0    + ((size_t)b * 64 + (t - 480)) * 128;
}

// K1: attT[side][b][d][t] = bias[d] + sum_k row[k] * W[d][k]  (transposed store for K2)
// row[] is wave-uniform -> scalar loads; no LDS, no barrier.
__global__ __launch_bounds__(128) void k_att(const float* __restrict__ v0, const float* __restrict__ v1,
                                             const float* __restrict__ v2, const float* __restrict__ vt,
                                             const float* __restrict__ vl,
                                             const float* __restrict__ Wt, const float* __restrict__ bt,
                                             const float* __restrict__ Wl, const float* __restrict__ bl,
                                             float* __restrict__ attT) {
    int t = blockIdx.x, b = blockIdx.y, side = blockIdx.z;
    int d = threadIdx.x;
    const float* row  = vd_row(side ? vl : vt, v0, v1, v2, b, t);
    const float* W    = side ? Wl : Wt;
    const float* bias = side ? bl : bt;
    float acc = bias[d];
    const f4* wrow = (const f4*)(W + d * 128);
    #pragma unroll
    for (int kc = 0; kc < 32; ++kc) {
        f4 wv = wrow[kc];
        #pragma unroll
        for (int j = 0; j < 4; ++j) acc += row[kc * 4 + j] * wv[j];
    }
    attT[((size_t)(side * 2 + b) * 128 + d) * 544 + t] = acc;
}

// K2: S[so][b][t][d]; so=0: mean over l of lrelu(tA+lA); so=1: mean over t.
// lrelu(x) = 0.505x + 0.495|x| => sum_l lrelu(c+o[l]) = 0.505*(544c + sum_o) + 0.495*sum|c+o[l]|
// otherr[] is wave-uniform -> scalar loads feed VALU; 2 VALU / element floor.
__global__ __launch_bounds__(256) void k_pair(const float* __restrict__ attT, float* __restrict__ S) {
    int d = blockIdx.x, b = blockIdx.y, so = blockIdx.z;
    int tid = threadIdx.x;
    const float* trow = attT + ((size_t)(0 * 2 + b) * 128 + d) * 544;
    const float* lrow = attT + ((size_t)(1 * 2 + b) * 128 + d) * 544;
    const float* selfr  = so ? lrow : trow;
    const float* otherr = so ? trow : lrow;
    __shared__ float red[4];
    float p = 0.f;
    for (int i = tid; i < 544; i += 256) p += otherr[i];
    #pragma unroll
    for (int off = 32; off > 0; off >>= 1) p += __shfl_down(p, off, 64);
    int lane = tid & 63, wid = tid >> 6;
    if (lane == 0) red[wid] = p;
    __syncthreads();
    float sum_o = red[0] + red[1] + red[2] + red[3];
    for (int t = tid; t < 544; t += 256) {
        float c = selfr[t];
        float s = 0.f;
        #pragma unroll 8
        for (int l = 0; l < 544; ++l) s += fabsf(c + otherr[l]);
        float res = (0.505f * (544.f * c + sum_o) + 0.495f * s) * (1.0f / 544.f);
        S[((size_t)(so * 2 + b) * 544 + t) * 128 + d] = res;
    }
}

// K3: atte = sigmoid(S @ Wa^T + ba) -> outputs 1/2; gated value -> gbuf (NO atomics).
// srow[] is wave-uniform -> scalar loads; one block per token = full occupancy.
__global__ __launch_bounds__(128) void k_atte(const float* __restrict__ S, const float* __restrict__ Wa,
                                              const float* __restrict__ ba,
                                              const float* __restrict__ v0, const float* __restrict__ v1,
                                              const float* __restrict__ v2, const float* __restrict__ vt,
                                              const float* __restrict__ vl,
                                              float* __restrict__ out, float* __restrict__ gbuf) {
    int t = blockIdx.x, b = blockIdx.y, side = blockIdx.z;
    int d = threadIdx.x;
    const float* srow = S + ((size_t)(side * 2 + b) * 544 + t) * 128;
    float acc = ba[d];
    const f4* wrow = (const f4*)(Wa + d * 128);
    #pragma unroll
    for (int kc = 0; kc < 32; ++kc) {
        f4 wv = wrow[kc];
        f4 sv = *(const f4*)(srow + kc * 4);
        acc += sv[0] * wv[0] + sv[1] * wv[1] + sv[2] * wv[2] + sv[3] * wv[3];
    }
    float atte = 1.f / (1.f + expf(-acc));
    out[4 + side * 139264 + ((size_t)b * 544 + t) * 128 + d] = atte;
    const float* vrow = vd_row(side ? vl : vt, v0, v1, v2, b, t);
    gbuf[((size_t)(side * 2 + b) * 544 + t) * 128 + d] = vrow[d] * (0.5f + atte);
}

// K4: x[b][c] = sum_t gbuf[side(c)][b][t][d(c)] — one (b,c) unit per wave, no atomics.
__global__ __launch_bounds__(256) void k_xr(const float* __restrict__ gbuf, float* __restrict__ x) {
    int wid = blockIdx.x * 4 + (threadIdx.x >> 6);   // 0..511
    int lane = threadIdx.x & 63;
    int b = wid >> 8, c = wid & 255;
    int side = c >> 7, dd = c & 127;
    const float* gp = gbuf + ((size_t)(side * 2 + b) * 544) * 128 + dd;
    float s = 0.f;
    #pragma unroll 4
    for (int t = lane; t < 544; t += 64) s += gp[(size_t)t * 128];
    #pragma unroll
    for (int off = 32; off > 0; off >>= 1) s += __shfl_down(s, off, 64);
    if (lane == 0) x[b * 256 + c] = s;
}

// FC layer: one wave per output element, K split across 64 lanes (f4 each), butterfly reduce.
template <int K, int OUT_TOTAL, bool LRELU>
__global__ __launch_bounds__(256) void k_fc(const float* __restrict__ in, const float* __restrict__ W,
                                            const float* __restrict__ bias, float* __restrict__ outv) {
    int wave = blockIdx.x * 4 + (threadIdx.x >> 6);
    int lane = threadIdx.x & 63;
    const int opb = OUT_TOTAL / 2;
    int b = wave / opb, o = wave % opb;
    const f4* wrow = (const f4*)(W + (size_t)o * K);
    const f4* inr  = (const f4*)(in + (size_t)b * K);
    float acc = 0.f;
    #pragma unroll
    for (int c = 0; c < K / 256; ++c) {
        f4 wv = wrow[c * 64 + lane];
        f4 iv = inr[c * 64 + lane];
        acc += wv[0] * iv[0] + wv[1] * iv[1] + wv[2] * iv[2] + wv[3] * iv[3];
    }
    #pragma unroll
    for (int off = 32; off > 0; off >>= 1) acc += __shfl_down(acc, off, 64);
    if (lane == 0) {
        acc += bias[o];
        if (LRELU) acc = acc > 0.f ? acc : 0.01f * acc;
        outv[wave] = acc;
    }
}

// K7: fc3 (both batches) + predict, one block (256 threads), LDS handoff.
__global__ __launch_bounds__(256) void k_f3p(const float* __restrict__ f2v, const float* __restrict__ W3,
                                             const float* __restrict__ b3, const float* __restrict__ Wo,
                                             const float* __restrict__ bo, float* __restrict__ out) {
    __shared__ float f3s[512];
    int tid = threadIdx.x;
    const f4* w3r = (const f4*)(W3 + (size_t)tid * 512);
    const f4* f20 = (const f4*)(f2v);
    const f4* f21 = (const f4*)(f2v + 512);
    float a0 = b3[tid], a1 = a0;
    #pragma unroll 4
    for (int c2 = 0; c2 < 128; ++c2) {
        f4 wv4 = w3r[c2];
        f4 i0 = f20[c2];
        f4 i1 = f21[c2];
        a0 += wv4[0]*i0[0] + wv4[1]*i0[1] + wv4[2]*i0[2] + wv4[3]*i0[3];
        a1 += wv4[0]*i1[0] + wv4[1]*i1[1] + wv4[2]*i1[2] + wv4[3]*i1[3];
    }
    f3s[tid]       = a0 > 0.f ? a0 : 0.01f * a0;
    f3s[256 + tid] = a1 > 0.f ? a1 : 0.01f * a1;
    __syncthreads();
    int wvid = tid >> 6, lane = tid & 63;
    int b = wvid >> 1, o = wvid & 1;                  // 4 waves -> 4 outputs
    f4 wo4 = ((const f4*)(Wo + o * 256))[lane];
    float acc = wo4[0]*f3s[b*256 + lane*4]     + wo4[1]*f3s[b*256 + lane*4 + 1]
              + wo4[2]*f3s[b*256 + lane*4 + 2] + wo4[3]*f3s[b*256 + lane*4 + 3];
    #pragma unroll
    for (int off = 32; off > 0; off >>= 1) acc += __shfl_down(acc, off, 64);
    if (lane == 0) out[b * 2 + o] = acc + bo[o];
}

extern "C" void kernel_launch(void* const* d_in, const int* in_sizes, int n_in,
                              void* d_out, int out_size, void* d_ws, size_t ws_size,
                              hipStream_t stream) {
    (void)in_sizes; (void)n_in; (void)out_size; (void)ws_size;
    const float* v0 = (const float*)d_in[0];
    const float* v1 = (const float*)d_in[1];
    const float* v2 = (const float*)d_in[2];
    const float* vt = (const float*)d_in[3];
    const float* vl = (const float*)d_in[4];
    const float* Wt = (const float*)d_in[5];
    const float* bt = (const float*)d_in[6];
    const float* Wl = (const float*)d_in[7];
    const float* bl = (const float*)d_in[8];
    const float* Wa = (const float*)d_in[9];
    const float* ba = (const float*)d_in[10];
    const float* W1 = (const float*)d_in[11];
    const float* b1 = (const float*)d_in[12];
    const float* W2 = (const float*)d_in[13];
    const float* b2 = (const float*)d_in[14];
    const float* W3 = (const float*)d_in[15];
    const float* b3 = (const float*)d_in[16];
    const float* Wo = (const float*)d_in[17];
    const float* bo = (const float*)d_in[18];

    float* ws   = (float*)d_ws;
    float* attT = ws;                 // [2][2][128][544] = 278528
    float* S    = ws + 278528;        // [2][2][544][128] = 278528
    float* gbuf = ws + 557056;        // [2][2][544][128] = 278528
    float* x    = ws + 835584;        // [2][256]
    float* f1v  = ws + 836096;        // [2][1024]
    float* f2v  = ws + 838144;        // [2][512]
    float* out = (float*)d_out;

    k_att<<<dim3(544, 2, 2), 128, 0, stream>>>(v0, v1, v2, vt, vl, Wt, bt, Wl, bl, attT);
    k_pair<<<dim3(128, 2, 2), 256, 0, stream>>>(attT, S);
    k_atte<<<dim3(544, 2, 2), 128, 0, stream>>>(S, Wa, ba, v0, v1, v2, vt, vl, out, gbuf);
    k_xr<<<128, 256, 0, stream>>>(gbuf, x);
    k_fc<256, 2048, true><<<512, 256, 0, stream>>>(x, W1, b1, f1v);
    k_fc<1024, 1024, true><<<256, 256, 0, stream>>>(f1v, W2, b2, f2v);
    k_f3p<<<1, 256, 0, stream>>>(f2v, W3, b3, Wo, bo, out);
}

// Round 8
// 86.900 us; speedup vs baseline: 3.0410x; 1.0563x over previous
//
#include <hip/hip_runtime.h>

typedef float f4 __attribute__((ext_vector_type(4)));

// Uniform row pointer into concatenated v_t_d / v_l_d:
// [vmain(384) | v1(64) | v2(32) | v0(64)] along tokens
__device__ __forceinline__ const float* vd_row(const float* vmain, const float* v0,
                                               const float* v1, const float* v2,
                                               int b, int t) {
    if (t < 384)      return vmain + ((size_t)b * 384 + t) * 128;
    else if (t < 448) return v1    + ((size_t)b * 64 + (t - 384)) * 128;
    else if (t < 480) return v2    + ((size_t)b * 32 + (t - 448)) * 128;
    else              return v0    + ((size_t)b * 64 + (t - 480)) * 128;
}

// K_A: fused att+pair. Block = (d, b); 256 threads.
// Phase A: att rows for both sides at this (b,d) -> LDS rows[1088] (zero redundancy:
//          these rows are consumed only by this block's pair units).
// Phase C: S[so][b][t][d] via lrelu(x)=0.505x+0.495|x| factorization.
// Blocks with d==0 also zero the x4 accumulation slabs (ordered before k_atte's atomics
// by the kernel boundary).
__global__ __launch_bounds__(256, 1) void k_attpair(
    const float* __restrict__ v0, const float* __restrict__ v1, const float* __restrict__ v2,
    const float* __restrict__ vt, const float* __restrict__ vl,
    const float* __restrict__ Wt, const float* __restrict__ bt,
    const float* __restrict__ Wl, const float* __restrict__ bl,
    float* __restrict__ S, float* __restrict__ x4)
{
    const int d = blockIdx.x, b = blockIdx.y;
    const int tid = threadIdx.x, lane = tid & 63, wvid = tid >> 6;
    __shared__ float rows[1088];            // [0..543]=trow, [544..1087]=lrow
    __shared__ float redv[2][4];

    if (d == 0) {
        for (int i = tid; i < 1024; i += 256)
            x4[(i >> 8) * 512 + b * 256 + (i & 255)] = 0.f;
    }

    // ---- Phase A: att rows (W row is block-uniform; v rows are per-lane gathers) ----
    #pragma unroll 1
    for (int side = 0; side < 2; ++side) {
        const float* W     = side ? Wl : Wt;
        const float* bias  = side ? bl : bt;
        const float* vmain = side ? vl : vt;
        f4 w[32];
        const f4* wrow = (const f4*)(W + d * 128);
        #pragma unroll
        for (int kc = 0; kc < 32; ++kc) w[kc] = wrow[kc];
        float bv = bias[d];
        for (int t = tid; t < 544; t += 256) {
            const f4* row = (const f4*)vd_row(vmain, v0, v1, v2, b, t);
            float a0 = 0.f, a1 = 0.f, a2 = 0.f, a3 = 0.f;
            #pragma unroll
            for (int kc = 0; kc < 32; kc += 4) {
                f4 r0 = row[kc], r1 = row[kc+1], r2 = row[kc+2], r3 = row[kc+3];
                a0 += r0[0]*w[kc][0]   + r0[1]*w[kc][1]   + r0[2]*w[kc][2]   + r0[3]*w[kc][3];
                a1 += r1[0]*w[kc+1][0] + r1[1]*w[kc+1][1] + r1[2]*w[kc+1][2] + r1[3]*w[kc+1][3];
                a2 += r2[0]*w[kc+2][0] + r2[1]*w[kc+2][1] + r2[2]*w[kc+2][2] + r2[3]*w[kc+2][3];
                a3 += r3[0]*w[kc+3][0] + r3[1]*w[kc+3][1] + r3[2]*w[kc+3][2] + r3[3]*w[kc+3][3];
            }
            rows[side * 544 + t] = bv + ((a0 + a1) + (a2 + a3));
        }
    }
    __syncthreads();

    // ---- Phase B: column sums of both rows ----
    float p0 = 0.f, p1 = 0.f;
    for (int i = tid; i < 544; i += 256) { p0 += rows[i]; p1 += rows[544 + i]; }
    #pragma unroll
    for (int off = 32; off > 0; off >>= 1) {
        p0 += __shfl_down(p0, off, 64);
        p1 += __shfl_down(p1, off, 64);
    }
    if (lane == 0) { redv[0][wvid] = p0; redv[1][wvid] = p1; }
    __syncthreads();
    const float sum_t = redv[0][0] + redv[0][1] + redv[0][2] + redv[0][3];
    const float sum_l = redv[1][0] + redv[1][1] + redv[1][2] + redv[1][3];

    // ---- Phase C: pairwise |.| means; otherr reads are LDS broadcasts ----
    #pragma unroll 1
    for (int so = 0; so < 2; ++so) {
        const float* selfr  = rows + so * 544;
        const float* otherr = rows + (1 - so) * 544;
        const float sum_o = so ? sum_t : sum_l;
        for (int t = tid; t < 544; t += 256) {
            float c = selfr[t];
            float s0 = 0.f, s1 = 0.f, s2 = 0.f, s3 = 0.f;
            for (int l = 0; l < 544; l += 4) {
                s0 += fabsf(c + otherr[l]);
                s1 += fabsf(c + otherr[l + 1]);
                s2 += fabsf(c + otherr[l + 2]);
                s3 += fabsf(c + otherr[l + 3]);
            }
            float s = (s0 + s1) + (s2 + s3);
            S[((size_t)(so * 2 + b) * 544 + t) * 128 + d] =
                (0.505f * (544.f * c + sum_o) + 0.495f * s) * (1.0f / 544.f);
        }
    }
}

// K_B: atte = sigmoid(S @ Wa^T + ba) -> outputs 1/2; gated value atomicAdd into
// slab x4[t&3] (chain depth 136). srow is block-uniform -> scalar loads.
__global__ __launch_bounds__(128) void k_atte(const float* __restrict__ S, const float* __restrict__ Wa,
                                              const float* __restrict__ ba,
                                              const float* __restrict__ v0, const float* __restrict__ v1,
                                              const float* __restrict__ v2, const float* __restrict__ vt,
                                              const float* __restrict__ vl,
                                              float* __restrict__ out, float* __restrict__ x4) {
    int t = blockIdx.x, b = blockIdx.y, side = blockIdx.z;
    int d = threadIdx.x;
    const float* srow = S + ((size_t)(side * 2 + b) * 544 + t) * 128;
    float acc = ba[d];
    const f4* wrow = (const f4*)(Wa + d * 128);
    #pragma unroll
    for (int kc = 0; kc < 32; ++kc) {
        f4 wv = wrow[kc];
        f4 sv = *(const f4*)(srow + kc * 4);
        acc += sv[0] * wv[0] + sv[1] * wv[1] + sv[2] * wv[2] + sv[3] * wv[3];
    }
    float atte = 1.f / (1.f + expf(-acc));
    out[4 + side * 139264 + ((size_t)b * 544 + t) * 128 + d] = atte;
    const float* vrow = vd_row(side ? vl : vt, v0, v1, v2, b, t);
    atomicAdd(&x4[(t & 3) * 512 + b * 256 + side * 128 + d], vrow[d] * (0.5f + atte));
}

// K_C: fc1 — one wave per output, x assembled from the 4 slabs on load.
__global__ __launch_bounds__(256) void k_fc1(const float* __restrict__ x4, const float* __restrict__ W1,
                                             const float* __restrict__ b1, float* __restrict__ f1v) {
    int wave = blockIdx.x * 4 + (threadIdx.x >> 6);   // 0..2047
    int lane = threadIdx.x & 63;
    int b = wave >> 10, o = wave & 1023;
    f4 iv = ((const f4*)(x4 + 0 * 512 + b * 256))[lane]
          + ((const f4*)(x4 + 1 * 512 + b * 256))[lane]
          + ((const f4*)(x4 + 2 * 512 + b * 256))[lane]
          + ((const f4*)(x4 + 3 * 512 + b * 256))[lane];
    f4 wv = ((const f4*)(W1 + (size_t)o * 256))[lane];
    float acc = wv[0]*iv[0] + wv[1]*iv[1] + wv[2]*iv[2] + wv[3]*iv[3];
    #pragma unroll
    for (int off = 32; off > 0; off >>= 1) acc += __shfl_down(acc, off, 64);
    if (lane == 0) {
        acc += b1[o];
        f1v[wave] = acc > 0.f ? acc : 0.01f * acc;
    }
}

// K_D: fc2 — one wave per output, K=1024 (4 f4/lane), butterfly reduce.
__global__ __launch_bounds__(256) void k_fc2(const float* __restrict__ f1v, const float* __restrict__ W2,
                                             const float* __restrict__ b2, float* __restrict__ f2v) {
    int wave = blockIdx.x * 4 + (threadIdx.x >> 6);   // 0..1023
    int lane = threadIdx.x & 63;
    int b = wave >> 9, o = wave & 511;
    const f4* w2r = (const f4*)(W2 + (size_t)o * 1024);
    const f4* i2r = (const f4*)(f1v + b * 1024);
    float acc = 0.f;
    #pragma unroll
    for (int c2 = 0; c2 < 4; ++c2) {
        f4 wv = w2r[c2 * 64 + lane];
        f4 iv = i2r[c2 * 64 + lane];
        acc += wv[0]*iv[0] + wv[1]*iv[1] + wv[2]*iv[2] + wv[3]*iv[3];
    }
    #pragma unroll
    for (int off = 32; off > 0; off >>= 1) acc += __shfl_down(acc, off, 64);
    if (lane == 0) {
        acc += b2[o];
        f2v[wave] = acc > 0.f ? acc : 0.01f * acc;
    }
}

// K_E: fc3 (both batches) + predict, one block (256 threads), LDS handoff.
__global__ __launch_bounds__(256) void k_f3p(const float* __restrict__ f2v, const float* __restrict__ W3,
                                             const float* __restrict__ b3, const float* __restrict__ Wo,
                                             const float* __restrict__ bo, float* __restrict__ out) {
    __shared__ float f3s[512];
    int tid = threadIdx.x;
    const f4* w3r = (const f4*)(W3 + (size_t)tid * 512);
    const f4* f20 = (const f4*)(f2v);
    const f4* f21 = (const f4*)(f2v + 512);
    float a0 = b3[tid], a1 = a0;
    #pragma unroll 4
    for (int c2 = 0; c2 < 128; ++c2) {
        f4 wv4 = w3r[c2];
        f4 i0 = f20[c2];
        f4 i1 = f21[c2];
        a0 += wv4[0]*i0[0] + wv4[1]*i0[1] + wv4[2]*i0[2] + wv4[3]*i0[3];
        a1 += wv4[0]*i1[0] + wv4[1]*i1[1] + wv4[2]*i1[2] + wv4[3]*i1[3];
    }
    f3s[tid]       = a0 > 0.f ? a0 : 0.01f * a0;
    f3s[256 + tid] = a1 > 0.f ? a1 : 0.01f * a1;
    __syncthreads();
    int wvid = tid >> 6, lane = tid & 63;
    int b = wvid >> 1, o = wvid & 1;                  // 4 waves -> 4 outputs
    f4 wo4 = ((const f4*)(Wo + o * 256))[lane];
    float acc = wo4[0]*f3s[b*256 + lane*4]     + wo4[1]*f3s[b*256 + lane*4 + 1]
              + wo4[2]*f3s[b*256 + lane*4 + 2] + wo4[3]*f3s[b*256 + lane*4 + 3];
    #pragma unroll
    for (int off = 32; off > 0; off >>= 1) acc += __shfl_down(acc, off, 64);
    if (lane == 0) out[b * 2 + o] = acc + bo[o];
}

extern "C" void kernel_launch(void* const* d_in, const int* in_sizes, int n_in,
                              void* d_out, int out_size, void* d_ws, size_t ws_size,
                              hipStream_t stream) {
    (void)in_sizes; (void)n_in; (void)out_size; (void)ws_size;
    const float* v0 = (const float*)d_in[0];
    const float* v1 = (const float*)d_in[1];
    const float* v2 = (const float*)d_in[2];
    const float* vt = (const float*)d_in[3];
    const float* vl = (const float*)d_in[4];
    const float* Wt = (const float*)d_in[5];
    const float* bt = (const float*)d_in[6];
    const float* Wl = (const float*)d_in[7];
    const float* bl = (const float*)d_in[8];
    const float* Wa = (const float*)d_in[9];
    const float* ba = (const float*)d_in[10];
    const float* W1 = (const float*)d_in[11];
    const float* b1 = (const float*)d_in[12];
    const float* W2 = (const float*)d_in[13];
    const float* b2 = (const float*)d_in[14];
    const float* W3 = (const float*)d_in[15];
    const float* b3 = (const float*)d_in[16];
    const float* Wo = (const float*)d_in[17];
    const float* bo = (const float*)d_in[18];

    float* ws   = (float*)d_ws;
    float* S    = ws;                 // [2][2][544][128] = 278528
    float* x4   = ws + 278528;        // [4][2][256]      = 2048
    float* f1v  = ws + 280576;        // [2][1024]
    float* f2v  = ws + 282624;        // [2][512]
    float* out = (float*)d_out;

    k_attpair<<<dim3(128, 2), 256, 0, stream>>>(v0, v1, v2, vt, vl, Wt, bt, Wl, bl, S, x4);
    k_atte<<<dim3(544, 2, 2), 128, 0, stream>>>(S, Wa, ba, v0, v1, v2, vt, vl, out, x4);
    k_fc1<<<512, 256, 0, stream>>>(x4, W1, b1, f1v);
    k_fc2<<<256, 256, 0, stream>>>(f1v, W2, b2, f2v);
    k_f3p<<<1, 256, 0, stream>>>(f2v, W3, b3, Wo, bo, out);
}